// Round 2
// baseline (1220.424 us; speedup 1.0000x reference)
//
#include <hip/hip_runtime.h>

#define HW 16384
#define NBLOCKS 16384

using short8 = __attribute__((ext_vector_type(8))) short;
using f32x4  = __attribute__((ext_vector_type(4))) float;

__device__ __forceinline__ unsigned short f2bf(float f) {
  unsigned int u = __float_as_uint(f);
  u += 0x7fffu + ((u >> 16) & 1u);
  return (unsigned short)(u >> 16);
}
__device__ __forceinline__ float bflo(unsigned int u) { return __uint_as_float(u << 16); }
__device__ __forceinline__ float bfhi(unsigned int u) { return __uint_as_float(u & 0xffff0000u); }

// XOR-swizzled LDS offset: row p (0..31), byte column cb (0..511).
// Preserves 16B groups (swizzle shifts are multiples of 16B) so ds_read_b128
// fragments stay contiguous; spreads 8 consecutive rows across all 32 banks.
#define LDSOFF(p, cb) (((p) << 9) + ((cb) ^ (((p) & 7) << 4)))

// ---------------------------------------------------------------------------
// Setup kernel: pre-swizzle all weights into bf16 MFMA B-fragment layout.
// For n-tile t, k-chunk kc: lane L holds W[n0 + (L&15)][k0 + (L>>4)*8 + j], j=0..7.
// ws ushort layout: [0..24576) QKV frags (proj*16+t), [24576..90112) W1, [90112..155648) W2.
__global__ void swzk(const float* __restrict__ Wq, const float* __restrict__ Wk,
                     const float* __restrict__ Wv, const float* __restrict__ W1,
                     const float* __restrict__ W2, unsigned short* __restrict__ out) {
  int f = blockIdx.x, t = threadIdx.x;
  int lane = t >> 2, j0 = (t & 3) << 1;
  int col = lane & 15, quad = lane >> 4;
  if (f < 48) {
    int proj = f >> 4, tt = f & 15;
    const float* W = proj == 0 ? Wq : (proj == 1 ? Wk : Wv);
    int row = ((tt & 1) << 4) + col;  // output channel within the 32x32 head matrix
    #pragma unroll
    for (int jj = 0; jj < 2; jj++) {
      int j = j0 + jj;
      out[(size_t)(f * 64 + lane) * 8 + j] = f2bf(W[row * 32 + (quad << 3) + j]);
    }
  } else if (f < 176) {
    int g = f - 48, tt = g >> 3, kc = g & 7;
    int row = (tt << 4) + col;
    #pragma unroll
    for (int jj = 0; jj < 2; jj++) {
      int j = j0 + jj;
      out[24576 + (size_t)(g * 64 + lane) * 8 + j] =
          f2bf(W1[row * 256 + (kc << 5) + (quad << 3) + j]);
    }
  } else {
    int g = f - 176, tt = g >> 3, kc = g & 7;
    int row = (tt << 4) + col;
    #pragma unroll
    for (int jj = 0; jj < 2; jj++) {
      int j = j0 + jj;
      out[90112 + (size_t)(g * 64 + lane) * 8 + j] =
          f2bf(W2[row * 256 + (kc << 5) + (quad << 3) + j]);
    }
  }
}

// ---------------------------------------------------------------------------
// Fused kernel: 32 pixels/block, 256 threads (4 waves).
// LDS (64KB): XS[0,16K) x/av, QS[16K,32K) q/h1, KS[32K,48K) k, VS[48K,64K) v.
__launch_bounds__(256, 2)
__global__ void fused_block(const float* __restrict__ x,
                            const float* __restrict__ bq,
                            const float* __restrict__ bk,
                            const float* __restrict__ bv,
                            const float* __restrict__ b1,
                            const float* __restrict__ b2,
                            const unsigned short* __restrict__ wsw,
                            float* __restrict__ out) {
  __shared__ unsigned char smem[65536];
  const int XS = 0, QS = 16384, KS = 32768, VS = 49152;
  int tid = threadIdx.x;
  int bid = blockIdx.x;
  int b = bid >> 9;                 // 512 blocks per image (16384/32)
  int hw0 = (bid & 511) << 5;
  const float* xb = x + ((size_t)b << 22) + hw0;

  // ---- stage x -> LDS bf16 (pairs of channels packed into dwords) ----
  {
    int p4 = (tid & 7) << 2;        // 4 consecutive pixels
    int c2 = (tid >> 3) << 1;       // even channel
    #pragma unroll
    for (int it = 0; it < 4; it++) {
      int c = c2 + it * 64;
      float4 ra = *(const float4*)(xb + (size_t)c * HW + p4);
      float4 rb = *(const float4*)(xb + (size_t)(c + 1) * HW + p4);
      float fa[4] = {ra.x, ra.y, ra.z, ra.w};
      float fb[4] = {rb.x, rb.y, rb.z, rb.w};
      #pragma unroll
      for (int i = 0; i < 4; i++) {
        unsigned int d = (unsigned int)f2bf(fa[i]) | ((unsigned int)f2bf(fb[i]) << 16);
        *(unsigned int*)(smem + XS + LDSOFF(p4 + i, c * 2)) = d;
      }
    }
  }
  __syncthreads();

  int lane = tid & 63, wv = tid >> 6;
  int col = lane & 15, quad = lane >> 4;

  // ---- QKV projections via MFMA (K=32 exactly one mfma per tile) ----
  // wave wv owns output channels [64*wv, 64*wv+64) == heads 2wv, 2wv+1.
  {
    const short8* qkvfr = (const short8*)wsw;
    short8 afr[2][2];
    #pragma unroll
    for (int m = 0; m < 2; m++)
      #pragma unroll
      for (int hh = 0; hh < 2; hh++) {
        int h = 2 * wv + hh;
        afr[m][hh] = *(const short8*)(smem + XS + LDSOFF(m * 16 + col, h * 64 + quad * 16));
      }
    #pragma unroll
    for (int proj = 0; proj < 3; proj++) {
      const float* bias = proj == 0 ? bq : (proj == 1 ? bk : bv);
      int base = proj == 0 ? QS : (proj == 1 ? KS : VS);
      #pragma unroll
      for (int ti = 0; ti < 4; ti++) {
        int t = 4 * wv + ti;
        short8 bfr = qkvfr[(proj * 16 + t) * 64 + lane];
        // bq/bk/bv are per-head EMB=32 vectors: index is the WITHIN-HEAD
        // output channel ((t&1)*16+col), NOT the global channel t*16+col.
        float bb = bias[((t & 1) << 4) + col];
        #pragma unroll
        for (int m = 0; m < 2; m++) {
          f32x4 acc = {0.f, 0.f, 0.f, 0.f};
          acc = __builtin_amdgcn_mfma_f32_16x16x32_bf16(afr[m][ti >> 1], bfr, acc, 0, 0, 0);
          #pragma unroll
          for (int r = 0; r < 4; r++) {
            float vvv = acc[r] + bb;
            if (proj == 0) vvv *= 0.17677669529663687f;  // fold 1/sqrt(emb) into q
            *(unsigned short*)(smem + base +
                LDSOFF(m * 16 + quad * 4 + r, (t * 16 + col) * 2)) = f2bf(vvv);
          }
        }
      }
    }
  }
  __syncthreads();

  // ---- per-pixel attention over 8 heads (VALU). thread = (pixel, head) ----
  // 8 lanes share p -> k/v LDS reads broadcast (conflict-free).
  {
    int p = tid >> 3, h = tid & 7;
    float qf[32];
    #pragma unroll
    for (int cc = 0; cc < 4; cc++) {
      uint4 u = *(const uint4*)(smem + QS + LDSOFF(p, h * 64 + cc * 16));
      unsigned int uu[4] = {u.x, u.y, u.z, u.w};
      #pragma unroll
      for (int j = 0; j < 4; j++) {
        qf[cc * 8 + 2 * j]     = bflo(uu[j]);
        qf[cc * 8 + 2 * j + 1] = bfhi(uu[j]);
      }
    }
    float sc[8];
    #pragma unroll
    for (int g = 0; g < 8; g++) {
      float s = 0.f;
      #pragma unroll
      for (int cc = 0; cc < 4; cc++) {
        uint4 u = *(const uint4*)(smem + KS + LDSOFF(p, g * 64 + cc * 16));
        unsigned int uu[4] = {u.x, u.y, u.z, u.w};
        #pragma unroll
        for (int j = 0; j < 4; j++) {
          s += qf[cc * 8 + 2 * j] * bflo(uu[j]);
          s += qf[cc * 8 + 2 * j + 1] * bfhi(uu[j]);
        }
      }
      sc[g] = s;
    }
    float mx = sc[0];
    #pragma unroll
    for (int g = 1; g < 8; g++) mx = fmaxf(mx, sc[g]);
    float sum = 0.f;
    #pragma unroll
    for (int g = 0; g < 8; g++) { sc[g] = __expf(sc[g] - mx); sum += sc[g]; }
    float inv = 1.f / sum;
    float av[32];
    #pragma unroll
    for (int j = 0; j < 32; j++) av[j] = 0.f;
    #pragma unroll
    for (int g = 0; g < 8; g++) {
      float wgt = sc[g] * inv;
      #pragma unroll
      for (int cc = 0; cc < 4; cc++) {
        uint4 u = *(const uint4*)(smem + VS + LDSOFF(p, g * 64 + cc * 16));
        unsigned int uu[4] = {u.x, u.y, u.z, u.w};
        #pragma unroll
        for (int j = 0; j < 4; j++) {
          av[cc * 8 + 2 * j]     += wgt * bflo(uu[j]);
          av[cc * 8 + 2 * j + 1] += wgt * bfhi(uu[j]);
        }
      }
    }
    // av -> XS region (x tile is dead)
    #pragma unroll
    for (int j = 0; j < 16; j++) {
      unsigned int d = (unsigned int)f2bf(av[2 * j]) |
                       ((unsigned int)f2bf(av[2 * j + 1]) << 16);
      *(unsigned int*)(smem + XS + LDSOFF(p, h * 64 + j * 4)) = d;
    }
  }
  __syncthreads();

  // ---- FFN layer 1: h1 = relu(av @ W1^T + b1), bf16 -> QS region ----
  const short8* w1fr = (const short8*)(wsw + 24576);
  const short8* w2fr = (const short8*)(wsw + 90112);
  f32x4 acc[2][4];
  #pragma unroll
  for (int m = 0; m < 2; m++)
    #pragma unroll
    for (int ti = 0; ti < 4; ti++) acc[m][ti] = (f32x4){0.f, 0.f, 0.f, 0.f};
  #pragma unroll
  for (int kc = 0; kc < 8; kc++) {
    short8 a0 = *(const short8*)(smem + XS + LDSOFF(col, kc * 64 + quad * 16));
    short8 a1 = *(const short8*)(smem + XS + LDSOFF(16 + col, kc * 64 + quad * 16));
    #pragma unroll
    for (int ti = 0; ti < 4; ti++) {
      short8 bfr = w1fr[((4 * wv + ti) * 8 + kc) * 64 + lane];
      acc[0][ti] = __builtin_amdgcn_mfma_f32_16x16x32_bf16(a0, bfr, acc[0][ti], 0, 0, 0);
      acc[1][ti] = __builtin_amdgcn_mfma_f32_16x16x32_bf16(a1, bfr, acc[1][ti], 0, 0, 0);
    }
  }
  #pragma unroll
  for (int ti = 0; ti < 4; ti++) {
    int n = (4 * wv + ti) * 16 + col;
    float bb = b1[n];
    #pragma unroll
    for (int m = 0; m < 2; m++)
      #pragma unroll
      for (int r = 0; r < 4; r++) {
        float vvv = fmaxf(acc[m][ti][r] + bb, 0.f);
        *(unsigned short*)(smem + QS + LDSOFF(m * 16 + quad * 4 + r, n * 2)) = f2bf(vvv);
      }
  }
  __syncthreads();

  // ---- FFN layer 2: out = h1 @ W2^T + b2 -> global (fp32) ----
  #pragma unroll
  for (int m = 0; m < 2; m++)
    #pragma unroll
    for (int ti = 0; ti < 4; ti++) acc[m][ti] = (f32x4){0.f, 0.f, 0.f, 0.f};
  #pragma unroll
  for (int kc = 0; kc < 8; kc++) {
    short8 a0 = *(const short8*)(smem + QS + LDSOFF(col, kc * 64 + quad * 16));
    short8 a1 = *(const short8*)(smem + QS + LDSOFF(16 + col, kc * 64 + quad * 16));
    #pragma unroll
    for (int ti = 0; ti < 4; ti++) {
      short8 bfr = w2fr[((4 * wv + ti) * 8 + kc) * 64 + lane];
      acc[0][ti] = __builtin_amdgcn_mfma_f32_16x16x32_bf16(a0, bfr, acc[0][ti], 0, 0, 0);
      acc[1][ti] = __builtin_amdgcn_mfma_f32_16x16x32_bf16(a1, bfr, acc[1][ti], 0, 0, 0);
    }
  }
  float* outb = out + ((size_t)b << 22) + hw0;
  #pragma unroll
  for (int ti = 0; ti < 4; ti++) {
    int n = (4 * wv + ti) * 16 + col;
    float bb = b2[n];
    #pragma unroll
    for (int m = 0; m < 2; m++)
      #pragma unroll
      for (int r = 0; r < 4; r++)
        outb[(size_t)n * HW + m * 16 + quad * 4 + r] = acc[m][ti][r] + bb;
  }
}

extern "C" void kernel_launch(void* const* d_in, const int* in_sizes, int n_in,
                              void* d_out, int out_size, void* d_ws, size_t ws_size,
                              hipStream_t stream) {
  const float* x  = (const float*)d_in[0];
  const float* Wq = (const float*)d_in[1];
  const float* bq = (const float*)d_in[2];
  const float* Wk = (const float*)d_in[3];
  const float* bk = (const float*)d_in[4];
  const float* Wv = (const float*)d_in[5];
  const float* bv = (const float*)d_in[6];
  const float* W1 = (const float*)d_in[7];
  const float* b1 = (const float*)d_in[8];
  const float* W2 = (const float*)d_in[9];
  const float* b2 = (const float*)d_in[10];
  unsigned short* wsw = (unsigned short*)d_ws;  // 311296 bytes used

  swzk<<<304, 256, 0, stream>>>(Wq, Wk, Wv, W1, W2, wsw);
  fused_block<<<NBLOCKS, 256, 0, stream>>>(x, bq, bk, bv, b1, b2,
                                           (const unsigned short*)wsw,
                                           (float*)d_out);
}